// Round 1
// baseline (290.188 us; speedup 1.0000x reference)
//
#include <hip/hip_runtime.h>

// B=4096, L=64, D=128, counts in [0,64].
#define DD   128
#define LLEN 64
#define TMAX 65                  // table rows: count values 0..64
#define ROWS_PER_BLK 4           // one wave (64 lanes) per batch row
#define TAB4 (TMAX * (DD / 4))   // 2080 float4 elements = 33280 B

typedef __attribute__((ext_vector_type(4))) float f32x4;

// Kernel 1: tab[a][e] = b2[e] + sum_d relu(a*W1[d]+b1[d]) * W2[d][e]
// (b2 folded in: out = tab[A0] + tab[A1] gives ... + 2*b2 as required)
__global__ void build_table_kernel(const float* __restrict__ W1,
                                   const float* __restrict__ b1,
                                   const float* __restrict__ W2,
                                   const float* __restrict__ b2,
                                   float* __restrict__ tab) {
    const int a = blockIdx.x;    // 0..64
    const int e = threadIdx.x;   // 0..127
    const float fa = (float)a;
    float acc = b2[e];
#pragma unroll 8
    for (int d = 0; d < DD; ++d) {
        float h = fmaxf(fmaf(fa, W1[d], b1[d]), 0.f);
        acc = fmaf(h, W2[d * DD + e], acc);
    }
    tab[a * DD + e] = acc;
}

// Kernel 2: 4 batch rows per block, one wave per row.
// LDS holds ONLY the table (33280 B). Counts and per-row indices live in
// registers; wave-uniform broadcasts via __shfl (readlane). Single sync.
__global__ __launch_bounds__(256, 4) void nif_main_kernel(
    const int* __restrict__ src_id, const int* __restrict__ dst_id,
    const int* __restrict__ src_nb, const int* __restrict__ dst_nb,
    const float* __restrict__ tab, float* __restrict__ out, int B) {
    __shared__ f32x4 TAB[TAB4];                      // 33280 B

    const int tid  = threadIdx.x;
    const int lane = tid & 63;
    const int w    = tid >> 6;                       // wave id 0..3
    const int b    = blockIdx.x * ROWS_PER_BLK + w;  // this wave's batch row

    // Issue per-row loads first so they overlap the table staging.
    const int vs  = src_nb[(size_t)b * LLEN + lane];
    const int vd  = dst_nb[(size_t)b * LLEN + lane];
    const int sid = src_id[b];
    const int did = dst_id[b];

    // Stage table into LDS (coalesced; 2080 f32x4 / 256 threads = 8.125 each)
    const f32x4* __restrict__ tabg = (const f32x4*)tab;
#pragma unroll
    for (int i = 0; i < 8; ++i) TAB[tid + 256 * i] = tabg[tid + 256 * i];
    if (tid < TAB4 - 2048) TAB[2048 + tid] = tabg[2048 + tid];

    // All-pairs counts, register-only (uniform shuffle index -> readlane).
    int c_src = 0, c_dos = 0, c_dst = 0, c_sod = 0;
#pragma unroll 8
    for (int j = 0; j < LLEN; ++j) {
        const int sj = __shfl(vs, j);
        const int dj = __shfl(vd, j);
        c_src += (sj == vs);   // count of S[i] in S
        c_dos += (dj == vs);   // count of S[i] in D
        c_dst += (dj == vd);   // count of D[i] in D
        c_sod += (sj == vd);   // count of D[i] in S
    }
    const int cd_sid = __popcll(__ballot(vd == sid));  // count of sid in D-row
    const int cs_did = __popcll(__ballot(vs == did));  // count of did in S-row
    const bool s_in_d = (cd_sid > 0);
    const bool same   = (sid == did);
    const bool c2     = (cs_did > 0) || (same && s_in_d);
    const int  v2     = (same && s_in_d) ? cd_sid : cs_did;
    // lane l of this wave holds the 4 table indices for output row l:
    const int A0 = c_src;                                  // src_app[...,0]
    const int A1 = (vs == did && c2) ? v2 : c_dos;         // src_app[...,1]
    const int C0 = (vd == sid && s_in_d) ? cd_sid : c_sod; // dst_app[...,0]
    const int C1 = c_dst;                                  // dst_app[...,1]

    __syncthreads();   // table staged

    // Store loop: uniform row l; lanes 0-31 emit src row, 32-63 emit dst row.
    // One store instruction = two dense 512B segments (1 KB total).
    const int e4 = lane & 31;        // float4 column 0..31
    const int lh = lane >> 5;        // 0 = src half, 1 = dst half
    const size_t src_base = (size_t)b * (LLEN * DD / 4);   // f32x4 units
    const size_t dst_base = src_base + (size_t)B * (LLEN * DD / 4);
    f32x4* __restrict__ myout =
        (f32x4*)out + (lh ? dst_base : src_base) + e4;

#pragma unroll 4
    for (int l = 0; l < LLEN; ++l) {
        const int a0 = __shfl(A0, l);      // uniform -> readlane broadcast
        const int a1 = __shfl(A1, l);
        const int c0 = __shfl(C0, l);
        const int c1 = __shfl(C1, l);
        const int p = lh ? c0 : a0;
        const int q = lh ? c1 : a1;
        const f32x4 t = TAB[p * 32 + e4] + TAB[q * 32 + e4];
        __builtin_nontemporal_store(t, myout + (size_t)l * 32);
    }
}

extern "C" void kernel_launch(void* const* d_in, const int* in_sizes, int n_in,
                              void* d_out, int out_size, void* d_ws, size_t ws_size,
                              hipStream_t stream) {
    const int*   src_id = (const int*)d_in[0];
    const int*   dst_id = (const int*)d_in[1];
    const int*   src_nb = (const int*)d_in[2];
    const int*   dst_nb = (const int*)d_in[3];
    const float* W1     = (const float*)d_in[4];
    const float* b1     = (const float*)d_in[5];
    const float* W2     = (const float*)d_in[6];
    const float* b2     = (const float*)d_in[7];
    float*       out    = (float*)d_out;
    float*       tab    = (float*)d_ws;   // 65*128 fp32 = 33280 B scratch

    const int B = in_sizes[0];

    build_table_kernel<<<TMAX, DD, 0, stream>>>(W1, b1, W2, b2, tab);
    nif_main_kernel<<<B / ROWS_PER_BLK, 256, 0, stream>>>(
        src_id, dst_id, src_nb, dst_nb, tab, out, B);
}

// Round 2
// 280.765 us; speedup vs baseline: 1.0336x; 1.0336x over previous
//
#include <hip/hip_runtime.h>

// B=4096, L=64, D=128, counts in [0,64].
#define DD   128
#define LLEN 64
#define TMAX 65                  // table rows: count values 0..64
#define ROWS_PER_BLK 8           // one wave (64 lanes) per batch row, 8 waves/block
#define TAB4 (TMAX * (DD / 4))   // 2080 float4 elements = 33280 B

typedef __attribute__((ext_vector_type(4))) float f32x4;

// Kernel 1: tab[a][e] = b2[e] + sum_d relu(a*W1[d]+b1[d]) * W2[d][e]
// (b2 folded in: out = tab[A0] + tab[A1] gives ... + 2*b2 as required)
__global__ void build_table_kernel(const float* __restrict__ W1,
                                   const float* __restrict__ b1,
                                   const float* __restrict__ W2,
                                   const float* __restrict__ b2,
                                   float* __restrict__ tab) {
    const int a = blockIdx.x;    // 0..64
    const int e = threadIdx.x;   // 0..127
    const float fa = (float)a;
    float acc = b2[e];
#pragma unroll 8
    for (int d = 0; d < DD; ++d) {
        float h = fmaxf(fmaf(fa, W1[d], b1[d]), 0.f);
        acc = fmaf(h, W2[d * DD + e], acc);
    }
    tab[a * DD + e] = acc;
}

// Kernel 2: 8 batch rows per block (512 threads), one wave per row.
// LDS holds ONLY the table (33280 B) -> 4 blocks/CU x 8 waves = 32 waves/CU
// (max occupancy; needs VGPR<=64, enforced by launch_bounds).
// Counts and per-row indices live in registers; single __syncthreads.
__global__ __launch_bounds__(512, 8) void nif_main_kernel(
    const int* __restrict__ src_id, const int* __restrict__ dst_id,
    const int* __restrict__ src_nb, const int* __restrict__ dst_nb,
    const float* __restrict__ tab, float* __restrict__ out, int B) {
    __shared__ f32x4 TAB[TAB4];                      // 33280 B

    const int tid  = threadIdx.x;
    const int lane = tid & 63;
    const int w    = tid >> 6;                       // wave id 0..7
    const int b    = blockIdx.x * ROWS_PER_BLK + w;  // this wave's batch row

    // Issue per-row loads first so they overlap the table staging.
    const int vs  = src_nb[(size_t)b * LLEN + lane];
    const int vd  = dst_nb[(size_t)b * LLEN + lane];
    const int sid = src_id[b];
    const int did = dst_id[b];

    // Stage table into LDS (coalesced; 2080 f32x4 / 512 threads = 4.06 each)
    const f32x4* __restrict__ tabg = (const f32x4*)tab;
#pragma unroll
    for (int i = 0; i < 4; ++i) TAB[tid + 512 * i] = tabg[tid + 512 * i];
    if (tid < TAB4 - 2048) TAB[2048 + tid] = tabg[2048 + tid];

    // All-pairs counts, register-only (uniform shuffle index -> readlane).
    int c_src = 0, c_dos = 0, c_dst = 0, c_sod = 0;
#pragma unroll 8
    for (int j = 0; j < LLEN; ++j) {
        const int sj = __shfl(vs, j);
        const int dj = __shfl(vd, j);
        c_src += (sj == vs);   // count of S[i] in S
        c_dos += (dj == vs);   // count of S[i] in D
        c_dst += (dj == vd);   // count of D[i] in D
        c_sod += (sj == vd);   // count of D[i] in S
    }
    const int cd_sid = __popcll(__ballot(vd == sid));  // count of sid in D-row
    const int cs_did = __popcll(__ballot(vs == did));  // count of did in S-row
    const bool s_in_d = (cd_sid > 0);
    const bool same   = (sid == did);
    const bool c2     = (cs_did > 0) || (same && s_in_d);
    const int  v2     = (same && s_in_d) ? cd_sid : cs_did;
    // lane l of this wave holds the 4 table indices for output row l:
    const int A0 = c_src;                                  // src_app[...,0]
    const int A1 = (vs == did && c2) ? v2 : c_dos;         // src_app[...,1]
    const int C0 = (vd == sid && s_in_d) ? cd_sid : c_sod; // dst_app[...,0]
    const int C1 = c_dst;                                  // dst_app[...,1]

    __syncthreads();   // table staged

    // Store loop: per iteration, this wave emits rows 2k (lanes 0-31) and
    // 2k+1 (lanes 32-63) of src — one CONTIGUOUS 1 KiB store — then the
    // same two rows of dst. Row indices via paired uniform readlanes.
    const int e4 = lane & 31;        // float4 column 0..31
    const int lh = lane >> 5;        // which of the two L-rows this half handles
    f32x4* __restrict__ out4 = (f32x4*)out;
    const size_t src_base = (size_t)b * (LLEN * DD / 4);   // f32x4 units
    const size_t dst_base = src_base + (size_t)B * (LLEN * DD / 4);

#pragma unroll 4
    for (int k = 0; k < 32; ++k) {
        const int l = 2 * k + lh;          // L-row 0..63
        const size_t idx4 = (size_t)l * 32 + e4;
        const int a0p = __shfl(A0, 2 * k), a0q = __shfl(A0, 2 * k + 1);
        const int a1p = __shfl(A1, 2 * k), a1q = __shfl(A1, 2 * k + 1);
        const int c0p = __shfl(C0, 2 * k), c0q = __shfl(C0, 2 * k + 1);
        const int c1p = __shfl(C1, 2 * k), c1q = __shfl(C1, 2 * k + 1);
        const int a0 = lh ? a0q : a0p;
        const int a1 = lh ? a1q : a1p;
        const int c0 = lh ? c0q : c0p;
        const int c1 = lh ? c1q : c1p;
        const f32x4 t = TAB[a0 * 32 + e4] + TAB[a1 * 32 + e4];
        out4[src_base + idx4] = t;
        const f32x4 u = TAB[c0 * 32 + e4] + TAB[c1 * 32 + e4];
        out4[dst_base + idx4] = u;
    }
}

extern "C" void kernel_launch(void* const* d_in, const int* in_sizes, int n_in,
                              void* d_out, int out_size, void* d_ws, size_t ws_size,
                              hipStream_t stream) {
    const int*   src_id = (const int*)d_in[0];
    const int*   dst_id = (const int*)d_in[1];
    const int*   src_nb = (const int*)d_in[2];
    const int*   dst_nb = (const int*)d_in[3];
    const float* W1     = (const float*)d_in[4];
    const float* b1     = (const float*)d_in[5];
    const float* W2     = (const float*)d_in[6];
    const float* b2     = (const float*)d_in[7];
    float*       out    = (float*)d_out;
    float*       tab    = (float*)d_ws;   // 65*128 fp32 = 33280 B scratch

    const int B = in_sizes[0];

    build_table_kernel<<<TMAX, DD, 0, stream>>>(W1, b1, W2, b2, tab);
    nif_main_kernel<<<B / ROWS_PER_BLK, 512, 0, stream>>>(
        src_id, dst_id, src_nb, dst_nb, tab, out, B);
}